// Round 12
// baseline (36.265 us; speedup 1.0000x reference)
//
#include <hip/hip_runtime.h>

#define NCLS 19
#define BINS 51
#define NPIX 4096
#define NFEAT 256
#define VCAP 256                   // staged values per wave (chunked beyond)
#define NSLOT 16
#define NBLK ((NFEAT / 4) * (NCLS - 1))   // 1152 blocks
#define TWO_PI_F 6.2831853071795864769f
#define LOG2E_F 1.4426950408889634f
#define EXP2F(v) __builtin_amdgcn_exp2f(v)

#define ST_AGENT(p, v) __hip_atomic_store((p), (v), __ATOMIC_RELAXED, __HIP_MEMORY_SCOPE_AGENT)
#define LD_AGENT(p)    __hip_atomic_load((p), __ATOMIC_RELAXED, __HIP_MEMORY_SCOPE_AGENT)

__device__ __forceinline__ unsigned mbcnt64(unsigned long long m) {
    unsigned r = __builtin_amdgcn_mbcnt_lo((unsigned)m, 0u);
    return __builtin_amdgcn_mbcnt_hi((unsigned)(m >> 32), r);
}

// ws layout: double slots[16] @ 0; int counter @ 128; int ncls[32] @ 192
// memset zeroes [0,132) each launch (slots + counter).
__global__ __launch_bounds__(256)
void hist_main(const float* __restrict__ x, const int* __restrict__ lab,
               double* __restrict__ slots, int* __restrict__ counter,
               int* __restrict__ ncls, float* __restrict__ out) {
    const int cm1  = blockIdx.y;                  // 0..17
    const int c    = cm1 + 1;
    const int tid  = threadIdx.x;
    const int lane = tid & 63;
    const int wv   = tid >> 6;                    // 0..3

    __shared__ unsigned short idx_lds[4][1024];   // class-c pixel indices (u16), 8 KB
    __shared__ __align__(16) float val[4][VCAP + 8];
    __shared__ int   n_sh[4];
    __shared__ float s_loss[4];
    __shared__ int   s_last;

    // ---- Phase 1: cooperative scan — wave wv compacts its 1024-pixel quarter ----
    const int4* labv = (const int4*)lab;
    unsigned short* myidx = idx_lds[wv];
    unsigned cnt = 0;

#define SUBSCAN(L, S)                                                 \
    {                                                                 \
        bool in = ((L) == c);                                         \
        unsigned long long m = __ballot(in);                          \
        if (in) myidx[cnt + mbcnt64(m)] = (unsigned short)(pbase + (S)); \
        cnt += (unsigned)__popcll(m);                                 \
    }

    #pragma unroll
    for (int it = 0; it < 4; ++it) {
        int b4    = wv * 256 + it * 64 + lane;
        int4 lv   = labv[b4];
        int pbase = b4 * 4;
        SUBSCAN(lv.x, 0)
        SUBSCAN(lv.y, 1)
        SUBSCAN(lv.z, 2)
        SUBSCAN(lv.w, 3)
    }
#undef SUBSCAN

    if (lane == 0) n_sh[wv] = (int)cnt;
    __syncthreads();                              // barrier 1

    const int n = n_sh[0] + n_sh[1] + n_sh[2] + n_sh[3];   // block-uniform
    const int f = blockIdx.x * 4 + wv;            // this wave's feature
    if (blockIdx.x == 0 && tid == 0) ST_AGENT(&ncls[c], n);
    if (tid < 4) s_loss[tid] = 0.f;

    if (n != 0) {
        // ---- Phase 2 (per wave): gather feature row + fused stats; stash chunk 0 ----
        const float* xrow  = x + (size_t)f * NPIX;
        float*       myval = val[wv];
        float s1 = 0.f, s2 = 0.f;
        {
            int pos = 0;
            #pragma unroll
            for (int s = 0; s < 4; ++s) {
                int ns_ = n_sh[s];
                const unsigned short* seg = idx_lds[s];
                for (int i = lane; i < ns_; i += 64) {
                    float v = xrow[seg[i]];       // scattered, L2-resident
                    int j = pos + i;
                    if (j < VCAP) myval[j] = v;
                    s1 += v;
                    s2 = fmaf(v, v, s2);
                }
                pos += ns_;
            }
        }
        #pragma unroll
        for (int off = 32; off; off >>= 1) {
            s1 += __shfl_xor(s1, off, 64);
            s2 += __shfl_xor(s2, off, 64);
        }
        const float fn  = (float)n;
        const float miu = s1 / fn;
        const float var = fmaxf(s2 / fn - miu * miu, 1e-12f);

        // ---- Phase 3 (per wave): KDE, lane = bin, poly-fma, 4 exp2 chains ----
        const float binv = -5.0f + 0.2f * (float)lane;
        const float cu   = (-12.5f / var) * LOG2E_F;
        const float bl   = -2.f * cu * binv;
        const float al   = cu * binv * binv;      // arg = (cu*v+bl)*v+al
        float a0 = 0.f, a1 = 0.f, a2 = 0.f, a3 = 0.f;

        for (int t0 = 0; t0 < n; t0 += VCAP) {
            if (t0 > 0) {                         // rare re-gather chunk (n > VCAP)
                int pos = 0;
                #pragma unroll
                for (int s = 0; s < 4; ++s) {
                    int ns_ = n_sh[s];
                    const unsigned short* seg = idx_lds[s];
                    for (int i = lane; i < ns_; i += 64) {
                        int j = pos + i - t0;
                        if (j >= 0 && j < VCAP) myval[j] = xrow[seg[i]];
                    }
                    pos += ns_;
                }
            }
            int ns  = n - t0; if (ns > VCAP) ns = VCAP;
            int ns4 = (ns + 3) & ~3;
            if (lane < ns4 - ns) myval[ns + lane] = 1e19f;   // sentinel: exp2 -> 0
            float* mv = myval;
            for (int i = 0; i < ns4; i += 4) {
                float4 v = *(const float4*)&mv[i];           // same-addr broadcast
                a0 += EXP2F(fmaf(fmaf(cu, v.x, bl), v.x, al));
                a1 += EXP2F(fmaf(fmaf(cu, v.y, bl), v.y, al));
                a2 += EXP2F(fmaf(fmaf(cu, v.z, bl), v.z, al));
                a3 += EXP2F(fmaf(fmaf(cu, v.w, bl), v.w, al));
            }
        }

        // ---- Phase 4 (per wave): normalize + smooth-L1 ----
        float kde = (a0 + a1) + (a2 + a3);
        float vs  = var * 0.04f;
        float dt  = binv - miu;
        float tg  = EXP2F(((-0.5f / var) * LOG2E_F) * (dt * dt));
        if (lane >= BINS) { kde = 0.f; tg = 0.f; }
        float sv = kde * rsqrtf(TWO_PI_F * vs);
        float tt = tg  * rsqrtf(TWO_PI_F * var);
        float ssum = sv, tsum = tt;
        #pragma unroll
        for (int off = 32; off; off >>= 1) {
            ssum += __shfl_xor(ssum, off, 64);
            tsum += __shfl_xor(tsum, off, 64);
        }
        float hist  = sv / fmaxf(ssum, 1e-12f);
        float tnorm = tt / tsum;
        float diff  = hist - tnorm;
        float ad    = fabsf(diff);
        float sl1   = (ad < 1.0f) ? 0.5f * diff * diff : (ad - 0.5f);
        if (lane >= BINS) sl1 = 0.f;
        #pragma unroll
        for (int off = 32; off; off >>= 1) sl1 += __shfl_xor(sl1, off, 64);
        if (lane == 0) s_loss[wv] = sl1;
    }
    __syncthreads();                              // barrier 2

    // ---- finale: atomic-only ordering (no threadfence / no L2 writeback) ----
    if (tid == 0) {
        if (n != 0) {
            float t = s_loss[0] + s_loss[1] + s_loss[2] + s_loss[3];
            atomicAdd(&slots[(blockIdx.y * 64 + blockIdx.x) & (NSLOT - 1)], (double)t);
        }
        // order: slot-add (and ncls store) must complete at the coherent point
        // before the ticket increments — atomics ack after performing.
        asm volatile("s_waitcnt vmcnt(0)" ::: "memory");
        int tk = __hip_atomic_fetch_add(counter, 1, __ATOMIC_RELAXED,
                                        __HIP_MEMORY_SCOPE_AGENT);
        s_last = (tk == NBLK - 1) ? 1 : 0;
    }
    __syncthreads();

    if (s_last && wv == 0) {                      // last block: reduce 16+18 scalars
        double s = (lane < NSLOT) ? LD_AGENT(&slots[lane]) : 0.0;
        int    a = (lane >= 1 && lane < NCLS) ? ((LD_AGENT(&ncls[lane]) > 0) ? 1 : 0) : 0;
        #pragma unroll
        for (int off = 32; off; off >>= 1) {
            s += __shfl_xor(s, off, 64);
            a += __shfl_xor(a, off, 64);
        }
        if (lane == 0) {
            double loss = s / (double)(NFEAT * BINS) / ((double)a + 1e-12);
            out[0] = (float)loss;
        }
    }
}

extern "C" void kernel_launch(void* const* d_in, const int* in_sizes, int n_in,
                              void* d_out, int out_size, void* d_ws, size_t ws_size,
                              hipStream_t stream) {
    const float* x   = (const float*)d_in[0];
    const int*   lab = (const int*)d_in[1];
    float* out       = (float*)d_out;
    double* slots    = (double*)d_ws;
    int*    counter  = (int*)((char*)d_ws + 128);
    int*    ncls     = (int*)((char*)d_ws + 192);

    (void)hipMemsetAsync(slots, 0, 132, stream);   // zero slots + counter each replay
    hipLaunchKernelGGL(hist_main, dim3(NFEAT / 4, NCLS - 1), dim3(256), 0, stream,
                       x, lab, slots, counter, ncls, out);
}

// Round 13
// 22.092 us; speedup vs baseline: 1.6415x; 1.6415x over previous
//
#include <hip/hip_runtime.h>

#define NCLS 19
#define BINS 51
#define NPIX 4096
#define NFEAT 256
#define VCAP 256                   // staged values per wave (chunked beyond)
#define NPART ((NFEAT / 4) * (NCLS - 1))   // 1152 per-block partials
#define TWO_PI_F 6.2831853071795864769f
#define LOG2E_F 1.4426950408889634f
#define EXP2F(v) __builtin_amdgcn_exp2f(v)

#define ST_AGENT(p, v) __hip_atomic_store((p), (v), __ATOMIC_RELAXED, __HIP_MEMORY_SCOPE_AGENT)
#define LD_AGENT(p)    __hip_atomic_load((p), __ATOMIC_RELAXED, __HIP_MEMORY_SCOPE_AGENT)

__device__ __forceinline__ unsigned mbcnt64(unsigned long long m) {
    unsigned r = __builtin_amdgcn_mbcnt_lo((unsigned)m, 0u);
    return __builtin_amdgcn_mbcnt_hi((unsigned)(m >> 32), r);
}

// ws layout: float partial[1152] @ 0 (4608 B); int ncls[32] @ 4608
// No memset node: every partial cell + ncls entry is overwritten every launch.
__global__ __launch_bounds__(256)
void hist_main(const float* __restrict__ x, const int* __restrict__ lab,
               float* __restrict__ partial, int* __restrict__ ncls) {
    const int cm1  = blockIdx.y;                  // 0..17
    const int c    = cm1 + 1;
    const int tid  = threadIdx.x;
    const int lane = tid & 63;
    const int wv   = tid >> 6;                    // 0..3

    __shared__ unsigned short idx_lds[4][1024];   // class-c pixel indices (u16), 8 KB
    __shared__ __align__(16) float val[4][VCAP + 8];
    __shared__ int   n_sh[4];
    __shared__ float s_loss[4];

    // ---- Phase 1: cooperative scan — wave wv compacts its 1024-pixel quarter ----
    const int4* labv = (const int4*)lab;
    unsigned short* myidx = idx_lds[wv];
    unsigned cnt = 0;

#define SUBSCAN(L, S)                                                 \
    {                                                                 \
        bool in = ((L) == c);                                         \
        unsigned long long m = __ballot(in);                          \
        if (in) myidx[cnt + mbcnt64(m)] = (unsigned short)(pbase + (S)); \
        cnt += (unsigned)__popcll(m);                                 \
    }

    #pragma unroll
    for (int it = 0; it < 4; ++it) {
        int b4    = wv * 256 + it * 64 + lane;
        int4 lv   = labv[b4];
        int pbase = b4 * 4;
        SUBSCAN(lv.x, 0)
        SUBSCAN(lv.y, 1)
        SUBSCAN(lv.z, 2)
        SUBSCAN(lv.w, 3)
    }
#undef SUBSCAN

    if (lane == 0) n_sh[wv] = (int)cnt;
    __syncthreads();                              // barrier 1

    const int n = n_sh[0] + n_sh[1] + n_sh[2] + n_sh[3];   // block-uniform
    const int f = blockIdx.x * 4 + wv;            // this wave's feature
    if (blockIdx.x == 0 && tid == 0) ST_AGENT(&ncls[c], n);

    if (n == 0) {                                 // still must overwrite our cell
        if (tid == 0) ST_AGENT(&partial[cm1 * (NFEAT / 4) + blockIdx.x], 0.f);
        return;                                   // block-uniform: safe
    }

    // ---- Phase 2 (per wave): gather feature row + fused stats; stash chunk 0 ----
    const float* xrow  = x + (size_t)f * NPIX;
    float*       myval = val[wv];
    float s1 = 0.f, s2 = 0.f;
    {
        int pos = 0;
        #pragma unroll
        for (int s = 0; s < 4; ++s) {
            int ns_ = n_sh[s];
            const unsigned short* seg = idx_lds[s];
            for (int i = lane; i < ns_; i += 64) {
                float v = xrow[seg[i]];           // scattered, L2-resident
                int j = pos + i;
                if (j < VCAP) myval[j] = v;
                s1 += v;
                s2 = fmaf(v, v, s2);
            }
            pos += ns_;
        }
    }
    #pragma unroll
    for (int off = 32; off; off >>= 1) {
        s1 += __shfl_xor(s1, off, 64);
        s2 += __shfl_xor(s2, off, 64);
    }
    const float fn  = (float)n;
    const float miu = s1 / fn;
    const float var = fmaxf(s2 / fn - miu * miu, 1e-12f);

    // ---- Phase 3 (per wave): KDE, lane = bin, poly-fma, 4 exp2 chains ----
    const float binv = -5.0f + 0.2f * (float)lane;
    const float cu   = (-12.5f / var) * LOG2E_F;  // -0.5/(var*0.04)*log2e
    const float bl   = -2.f * cu * binv;
    const float al   = cu * binv * binv;          // arg = (cu*v+bl)*v+al
    float a0 = 0.f, a1 = 0.f, a2 = 0.f, a3 = 0.f;

    for (int t0 = 0; t0 < n; t0 += VCAP) {
        if (t0 > 0) {                             // rare re-gather chunk (n > VCAP)
            int pos = 0;
            #pragma unroll
            for (int s = 0; s < 4; ++s) {
                int ns_ = n_sh[s];
                const unsigned short* seg = idx_lds[s];
                for (int i = lane; i < ns_; i += 64) {
                    int j = pos + i - t0;
                    if (j >= 0 && j < VCAP) myval[j] = xrow[seg[i]];
                }
                pos += ns_;
            }
        }
        int ns  = n - t0; if (ns > VCAP) ns = VCAP;
        int ns4 = (ns + 3) & ~3;
        if (lane < ns4 - ns) myval[ns + lane] = 1e19f;   // sentinel: exp2 -> 0
        #pragma unroll 2
        for (int i = 0; i < ns4; i += 4) {
            float4 v = *(const float4*)&myval[i];        // same-addr broadcast read
            a0 += EXP2F(fmaf(fmaf(cu, v.x, bl), v.x, al));
            a1 += EXP2F(fmaf(fmaf(cu, v.y, bl), v.y, al));
            a2 += EXP2F(fmaf(fmaf(cu, v.z, bl), v.z, al));
            a3 += EXP2F(fmaf(fmaf(cu, v.w, bl), v.w, al));
        }
    }

    // ---- Phase 4 (per wave): normalize + smooth-L1 ----
    float kde = (a0 + a1) + (a2 + a3);
    float vs  = var * 0.04f;
    float dt  = binv - miu;
    float tg  = EXP2F(((-0.5f / var) * LOG2E_F) * (dt * dt));
    if (lane >= BINS) { kde = 0.f; tg = 0.f; }
    float sv = kde * rsqrtf(TWO_PI_F * vs);
    float tt = tg  * rsqrtf(TWO_PI_F * var);
    float ssum = sv, tsum = tt;
    #pragma unroll
    for (int off = 32; off; off >>= 1) {
        ssum += __shfl_xor(ssum, off, 64);
        tsum += __shfl_xor(tsum, off, 64);
    }
    float hist  = sv / fmaxf(ssum, 1e-12f);
    float tnorm = tt / tsum;
    float diff  = hist - tnorm;
    float ad    = fabsf(diff);
    float sl1   = (ad < 1.0f) ? 0.5f * diff * diff : (ad - 0.5f);
    if (lane >= BINS) sl1 = 0.f;
    #pragma unroll
    for (int off = 32; off; off >>= 1) sl1 += __shfl_xor(sl1, off, 64);
    if (lane == 0) s_loss[wv] = sl1;
    __syncthreads();                              // barrier 2 (block-uniform path)

    if (tid == 0) {
        float t = s_loss[0] + s_loss[1] + s_loss[2] + s_loss[3];
        ST_AGENT(&partial[cm1 * (NFEAT / 4) + blockIdx.x], t);
    }
}

// ---- finale: deterministic f64 reduction of 1152 cells (agent loads) ----
__global__ __launch_bounds__(256)
void hist_final(const float* __restrict__ partial, const int* __restrict__ ncls,
                float* __restrict__ out) {
    const int tid = threadIdx.x, lane = tid & 63, wave = tid >> 6;
    __shared__ double sd[4];

    double s = 0.0;
    for (int i = tid; i < NPART; i += 256)
        s += (double)LD_AGENT(&partial[i]);
    #pragma unroll
    for (int off = 32; off; off >>= 1) s += __shfl_xor(s, off, 64);
    if (lane == 0) sd[wave] = s;
    __syncthreads();
    if (tid == 0) {
        double tot = sd[0] + sd[1] + sd[2] + sd[3];
        int active = 0;
        for (int cc = 1; cc < NCLS; ++cc) active += (LD_AGENT(&ncls[cc]) > 0) ? 1 : 0;
        double loss = tot / (double)(NFEAT * BINS) / ((double)active + 1e-12);
        out[0] = (float)loss;
    }
}

extern "C" void kernel_launch(void* const* d_in, const int* in_sizes, int n_in,
                              void* d_out, int out_size, void* d_ws, size_t ws_size,
                              hipStream_t stream) {
    const float* x   = (const float*)d_in[0];
    const int*   lab = (const int*)d_in[1];
    float* out       = (float*)d_out;
    float* partial   = (float*)d_ws;
    int*   ncls      = (int*)((char*)d_ws + 4608);

    hipLaunchKernelGGL(hist_main, dim3(NFEAT / 4, NCLS - 1), dim3(256), 0, stream,
                       x, lab, partial, ncls);
    hipLaunchKernelGGL(hist_final, dim3(1), dim3(256), 0, stream,
                       partial, ncls, out);
}